// Round 10
// baseline (428.128 us; speedup 1.0000x reference)
//
#include <hip/hip_runtime.h>
#include <hip/hip_bf16.h>

#define NPIX 6400
#define IMW 80
#define IMH 80

typedef __attribute__((ext_vector_type(8))) short short8;
typedef __attribute__((ext_vector_type(4))) float floatx4;

__device__ __forceinline__ float silu_f(float v) {
    return v / (1.0f + __expf(-v));
}
__device__ __forceinline__ unsigned short f2bf(float v) {
    __hip_bfloat16 h = __float2bfloat16(v);
    return *(unsigned short*)&h;
}

// ============ prep: swizzle weights into MFMA-fragment-contiguous layout ============
// layout: W[mtile][kstep][lane][8] bf16; lane=quad*16+col holds A[co=mt*16+col][k=ks*32+quad*8 ..+8]

// W1 [256co][256k] -> Wt1s: 16 mt x 8 ks x 64 lane x 8
__global__ __launch_bounds__(256) void prep_swz1(
    const float* __restrict__ W1, __hip_bfloat16* __restrict__ Wt1s)
{
    int t = blockIdx.x * 256 + threadIdx.x;     // 8192 total
    int mt = t >> 9, rem = t & 511;
    int ks = rem >> 6, lane = rem & 63;
    int col = lane & 15, quad = lane >> 4;
    const float* src = W1 + (size_t)(mt * 16 + col) * 256 + ks * 32 + quad * 8;
    unsigned short pk[8];
    #pragma unroll
    for (int j = 0; j < 8; ++j) pk[j] = f2bf(src[j]);
    *(uint4*)(Wt1s + (size_t)t * 8) = *(uint4*)pk;
}

// W2 [256co][384k] -> Wt2s: 16 mt x 12 ks x 64 x 8
__global__ __launch_bounds__(256) void prep_swz2(
    const float* __restrict__ W2, __hip_bfloat16* __restrict__ Wt2s)
{
    int t = blockIdx.x * 256 + threadIdx.x;     // 12288 total
    int mt = t / 768, rem = t % 768;
    int ks = rem >> 6, lane = rem & 63;
    int col = lane & 15, quad = lane >> 4;
    const float* src = W2 + (size_t)(mt * 16 + col) * 384 + ks * 32 + quad * 8;
    unsigned short pk[8];
    #pragma unroll
    for (int j = 0; j < 8; ++j) pk[j] = f2bf(src[j]);
    *(uint4*)(Wt2s + (size_t)t * 8) = *(uint4*)pk;
}

// W_exp [e][co][ci][3][3] -> Wts: e x 8 gmt x 36 s x 64 x 8; s = tap*4 + ci/32
__global__ __launch_bounds__(256) void prep_swzE(
    const float* __restrict__ Wexp, __hip_bfloat16* __restrict__ Wts)
{
    int t = blockIdx.x * 256 + threadIdx.x;     // 73728 total
    int e = t / 18432, rem = t % 18432;
    int gmt = rem / 2304, rem2 = rem % 2304;
    int s = rem2 >> 6, lane = rem2 & 63;
    int col = lane & 15, quad = lane >> 4;
    int tap = s >> 2;
    int cib = (s & 3) * 32 + quad * 8;
    int co  = gmt * 16 + col;
    const float* src = Wexp + ((size_t)(e * 128 + co) * 128 + cib) * 9 + tap;
    unsigned short pk[8];
    #pragma unroll
    for (int j = 0; j < 8; ++j) pk[j] = f2bf(src[j * 9]);
    *(uint4*)(Wts + (size_t)t * 8) = *(uint4*)pk;
}

// ---------------- FUSED transpose + cv1 (R6, verified) -----------------------------------
__global__ __launch_bounds__(256, 2) void cv1_fused(
    const float* __restrict__ x, const __hip_bfloat16* __restrict__ Wt1s,
    const float* __restrict__ b1, __hip_bfloat16* __restrict__ catT,
    float* __restrict__ pooled)
{
    __shared__ __align__(16) unsigned short xs[128][256];   // 65536 B
    const int b  = blockIdx.y;
    const int p0 = blockIdx.x * 128;
    const int tid = threadIdx.x;

    // ---- stage: thread = one ci row (line-granular streams), 32 float4 along pix ----
    {
        const int ci = tid;
        const int slotbase = (ci >> 3) ;         // 16B slot index before swizzle
        const int cilo = ci & 7;
        const float* src = x + ((size_t)b * 256 + ci) * NPIX + p0;
        #pragma unroll
        for (int pg = 0; pg < 32; ++pg) {
            float4 v = *(const float4*)(src + pg * 4);
            float vv[4] = {v.x, v.y, v.z, v.w};
            #pragma unroll
            for (int r = 0; r < 4; ++r) {
                int pix = pg * 4 + r;
                int slot = slotbase ^ ((pix & 7) << 2);
                xs[pix][slot * 8 + cilo] = f2bf(vv[r]);
            }
        }
    }
    __syncthreads();

    // ---- GEMM: identical tiling to old cv1; B-fragments from LDS ----
    const int wave = tid >> 6, lane = tid & 63;
    const int col = lane & 15, quad = lane >> 4;
    const int cohalf  = (wave & 1) * 128;
    const int gmt0    = (wave & 1) * 8;
    const int pixhalf = (wave >> 1) * 64;

    __hip_bfloat16* ct = catT + (size_t)b * NPIX * 384;
    int pp[4], pl[4];
    #pragma unroll
    for (int nt = 0; nt < 4; ++nt) {
        pl[nt] = pixhalf + nt * 16 + col;         // local pixel 0..127
        pp[nt] = p0 + pl[nt];                     // global pixel
    }

    floatx4 acc[8][4] = {};

    #pragma unroll
    for (int ks = 0; ks < 8; ++ks) {
        short8 bf[4];
        #pragma unroll
        for (int nt = 0; nt < 4; ++nt) {
            int slot = (ks * 4 + quad) ^ ((pl[nt] & 7) << 2);
            bf[nt] = *(const short8*)&xs[pl[nt]][slot * 8];
        }
        #pragma unroll
        for (int mt = 0; mt < 8; ++mt) {
            short8 af = *(const short8*)&Wt1s[(size_t)(((gmt0 + mt) * 8 + ks) * 64 + lane) * 8];
            #pragma unroll
            for (int nt = 0; nt < 4; ++nt)
                acc[mt][nt] = __builtin_amdgcn_mfma_f32_16x16x32_bf16(af, bf[nt], acc[mt][nt], 0, 0, 0);
        }
    }

    // epilogue: bias + silu, store y -> catT slots 0..255; pooled from m-half
    #pragma unroll
    for (int mt = 0; mt < 8; ++mt) {
        const int cobase = cohalf + mt * 16 + quad * 4;
        float bias[4];
        #pragma unroll
        for (int r = 0; r < 4; ++r) bias[r] = b1[cobase + r];
        float v[4][4];
        #pragma unroll
        for (int nt = 0; nt < 4; ++nt) {
            unsigned short pk[4];
            #pragma unroll
            for (int r = 0; r < 4; ++r) {
                v[nt][r] = silu_f(acc[mt][nt][r] + bias[r]);
                pk[r] = f2bf(v[nt][r]);
            }
            *(uint2*)&ct[(size_t)pp[nt] * 384 + cobase] = *(uint2*)pk;
        }
        if (cohalf == 128) {
            #pragma unroll
            for (int r = 0; r < 4; ++r) {
                float s = v[0][r] + v[1][r] + v[2][r] + v[3][r];
                #pragma unroll
                for (int m = 1; m < 16; m <<= 1)
                    s += __shfl_xor(s, m, 64);
                if (col == 0)
                    atomicAdd(&pooled[b * 128 + (cobase - 128) + r], s * (1.0f / NPIX));
            }
        }
    }
}

// ---------------- router ----------------
__global__ __launch_bounds__(64) void router_kernel(
    const float* __restrict__ pooled, const float* __restrict__ Wr,
    const float* __restrict__ br, int* __restrict__ sel_idx, float* __restrict__ sel_w)
{
    __shared__ float lg[16][4];
    int tid = threadIdx.x;
    int b = tid >> 2, e = tid & 3;
    float s = br[e];
    for (int c2 = 0; c2 < 128; c2++)
        s += pooled[b * 128 + c2] * Wr[e * 128 + c2];
    lg[b][e] = s;
    __syncthreads();
    if (tid < 16) {
        int bb = tid;
        float l[4]; float mx = -1e30f;
        #pragma unroll
        for (int i = 0; i < 4; i++) { l[i] = lg[bb][i]; mx = fmaxf(mx, l[i]); }
        float p[4]; float sum = 0.f;
        #pragma unroll
        for (int i = 0; i < 4; i++) { p[i] = __expf(l[i] - mx); sum += p[i]; }
        #pragma unroll
        for (int i = 0; i < 4; i++) p[i] /= sum;
        int i1 = 0;
        for (int i = 1; i < 4; i++) if (p[i] > p[i1]) i1 = i;
        int i2 = (i1 == 0) ? 1 : 0;
        for (int i = 0; i < 4; i++) if (i != i1 && p[i] > p[i2]) i2 = i;
        float inv = 1.0f / (p[i1] + p[i2]);
        sel_idx[bb * 2 + 0] = i1; sel_idx[bb * 2 + 1] = i2;
        sel_w[bb * 2 + 0] = p[i1] * inv; sel_w[bb * 2 + 1] = p[i2] * inv;
    }
}

// ---------------- FUSED expert conv + cv2 -------------------------------------------------
// ROUND 9: expert's moe output was written to catT (26MB) only to be re-read by cv2 for
// the SAME 128-pixel tile (cv2 needs no halo -> dependency is block-local). Fuse:
// phase 1 = R9's expert (weight LDS staging per tap, verified 112.6us, MfmaUtil 22);
// after the tap loop the weights in wl are dead -> reuse as moeL[128pix][128ci] bf16
// (32KB, slot^(pix&7) swizzle: uniform 8 lanes/bank-set = structural minimum both sides);
// phase 2 = cv2's K=384 GEMM with ks 8..11 (moe) from LDS, ks 0..7 (a,m) from L2-hot catT.
// Deletes 26MB moe write + 26MB moe read + one kernel boundary. LDS stays 64KB (2 blk/CU);
// phase-1/phase-2 acc lifetimes disjoint.
__global__ __launch_bounds__(256, 2) void expert_cv2(
    const __hip_bfloat16* __restrict__ catT, const __hip_bfloat16* __restrict__ Wts,
    const float* __restrict__ bexp, const int* __restrict__ sel_idx,
    const float* __restrict__ sel_w, const __hip_bfloat16* __restrict__ Wt2s,
    const float* __restrict__ b2, float* __restrict__ out)
{
    // 64 chunks of 64lane x 8bf16 = 64KB weights (phase 1); reused as moeL (32KB) after
    __shared__ __align__(16) __hip_bfloat16 wl[64 * 512];

    const int id  = blockIdx.x;
    const int xcd = id & 7, j = id >> 3;
    const int lin = xcd * 100 + j;
    const int b   = lin / 50;
    const int p0  = (lin % 50) * 128;

    const int e0 = sel_idx[b * 2 + 0], e1 = sel_idx[b * 2 + 1];
    const float g0 = sel_w[b * 2 + 0], g1 = sel_w[b * 2 + 1];

    const int tid  = threadIdx.x;
    const int wave = tid >> 6, lane = tid & 63;
    const int col  = lane & 15, quad = lane >> 4;
    const int cohalf  = (wave & 1) * 64;      // phase-1 expert co half
    const int gmt0    = (wave & 1) * 4;
    const int pixhalf = (wave >> 1) * 64;     // shared by both phases

    const __hip_bfloat16* ct = catT + (size_t)b * NPIX * 384;
    const __hip_bfloat16* wbase[2];
    wbase[0] = Wts + (size_t)e0 * (8 * 36 * 64 * 8);
    wbase[1] = Wts + (size_t)e1 * (8 * 36 * 64 * 8);

    int pp[4], prow[4], pcol[4];
    #pragma unroll
    for (int nt = 0; nt < 4; ++nt) {
        pp[nt]   = p0 + pixhalf + nt * 16 + col;
        prow[nt] = pp[nt] / IMW;
        pcol[nt] = pp[nt] % IMW;
    }

    // ================= phase 1: expert conv =================
    {
        floatx4 acc[2][4][4] = {};   // [expert][mt][nt]

        for (int tap = 0; tap < 9; ++tap) {
            const int dyy = tap / 3 - 1, dxx = tap % 3 - 1;

            __syncthreads();   // previous tap's wl reads complete before overwrite (WAR)
            #pragma unroll
            for (int i = 0; i < 16; ++i) {
                int c   = wave * 16 + i;          // 0..63
                int ce  = c >> 5;                 // expert 0/1
                int rem = c & 31;
                int gmt = rem >> 2, ss3 = rem & 3;
                const __hip_bfloat16* srcp = wbase[ce]
                    + (size_t)((gmt * 36 + tap * 4 + ss3) * 64 + lane) * 8;
                __hip_bfloat16* dstp = &wl[c * 512];           // wave-uniform chunk base
                __builtin_amdgcn_global_load_lds(
                    (const __attribute__((address_space(1))) unsigned int*)srcp,
                    (__attribute__((address_space(3))) unsigned int*)dstp, 16, 0, 0);
            }
            __syncthreads();   // drains vmcnt -> wl visible to all waves

            bool valid[4];
            const __hip_bfloat16* bbase[4];
            #pragma unroll
            for (int nt = 0; nt < 4; ++nt) {
                int ir = prow[nt] + dyy, ic = pcol[nt] + dxx;
                valid[nt] = ((unsigned)ir < IMH) && ((unsigned)ic < IMW);
                bbase[nt] = ct + (size_t)(ir * IMW + ic) * 384 + 128 + quad * 8;
            }
            #pragma unroll
            for (int ss = 0; ss < 4; ++ss) {
                short8 bf[4];
                #pragma unroll
                for (int nt = 0; nt < 4; ++nt) {
                    int4 vv = {0, 0, 0, 0};
                    if (valid[nt]) vv = *(const int4*)(bbase[nt] + ss * 32);
                    bf[nt] = *(short8*)&vv;
                }
                __builtin_amdgcn_s_setprio(1);
                #pragma unroll
                for (int e = 0; e < 2; ++e) {
                    #pragma unroll
                    for (int mt = 0; mt < 4; ++mt) {
                        short8 af = *(const short8*)&wl[(size_t)((e * 8 + gmt0 + mt) * 4 + ss) * 512
                                                        + lane * 8];
                        #pragma unroll
                        for (int nt = 0; nt < 4; ++nt)
                            acc[e][mt][nt] = __builtin_amdgcn_mfma_f32_16x16x32_bf16(
                                af, bf[nt], acc[e][mt][nt], 0, 0, 0);
                    }
                }
                __builtin_amdgcn_s_setprio(0);
            }
        }

        // epilogue 1: gate-weighted moe -> LDS moeL (reuses wl; weights dead)
        __syncthreads();   // all waves done reading wl weights
        #pragma unroll
        for (int mt = 0; mt < 4; ++mt) {
            const int cobase = cohalf + mt * 16 + quad * 4;    // 0..124
            const int slot16 = cobase >> 3;                    // 0..15
            const int off    = cobase & 7;                     // 0 or 4
            #pragma unroll
            for (int nt = 0; nt < 4; ++nt) {
                const int pixL = pixhalf + nt * 16 + col;      // 0..127
                unsigned short pk[4];
                #pragma unroll
                for (int r = 0; r < 4; ++r) {
                    int coo = cobase + r;
                    float vb0 = bexp[e0 * 128 + coo];
                    float vb1 = bexp[e1 * 128 + coo];
                    float v = g0 * silu_f(acc[0][mt][nt][r] + vb0)
                            + g1 * silu_f(acc[1][mt][nt][r] + vb1);
                    pk[r] = f2bf(v);
                }
                *(uint2*)&wl[(size_t)pixL * 128 + ((slot16 ^ (pixL & 7)) * 8) + off] = *(uint2*)pk;
            }
        }
        __syncthreads();   // moeL visible to all waves
    }

    // ================= phase 2: cv2 (K=384; moe from LDS) =================
    {
        const int cohalf2 = (wave & 1) * 128;
        const int gmt0_2  = (wave & 1) * 8;

        floatx4 acc2[8][4] = {};

        #pragma unroll
        for (int ks = 0; ks < 12; ++ks) {
            short8 bf[4];
            if (ks < 8) {
                #pragma unroll
                for (int nt = 0; nt < 4; ++nt)
                    bf[nt] = *(const short8*)&ct[(size_t)pp[nt] * 384 + ks * 32 + quad * 8];
            } else {
                #pragma unroll
                for (int nt = 0; nt < 4; ++nt) {
                    const int pl = pixhalf + nt * 16 + col;
                    const int s0 = (ks - 8) * 4 + quad;
                    bf[nt] = *(const short8*)&wl[(size_t)pl * 128 + ((s0 ^ (pl & 7)) * 8)];
                }
            }
            #pragma unroll
            for (int mt = 0; mt < 8; ++mt) {
                short8 af = *(const short8*)&Wt2s[(size_t)(((gmt0_2 + mt) * 12 + ks) * 64 + lane) * 8];
                #pragma unroll
                for (int nt = 0; nt < 4; ++nt)
                    acc2[mt][nt] = __builtin_amdgcn_mfma_f32_16x16x32_bf16(af, bf[nt], acc2[mt][nt], 0, 0, 0);
            }
        }

        #pragma unroll
        for (int mt = 0; mt < 8; ++mt) {
            const int cobase = cohalf2 + mt * 16 + quad * 4;
            #pragma unroll
            for (int r = 0; r < 4; ++r) {
                float bias = b2[cobase + r];
                size_t rowb = ((size_t)b * 256 + cobase + r) * NPIX;
                #pragma unroll
                for (int nt = 0; nt < 4; ++nt)
                    out[rowb + pp[nt]] = silu_f(acc2[mt][nt][r] + bias);
            }
        }
    }
}

extern "C" void kernel_launch(void* const* d_in, const int* in_sizes, int n_in,
                              void* d_out, int out_size, void* d_ws, size_t ws_size,
                              hipStream_t stream)
{
    (void)in_sizes; (void)n_in; (void)out_size; (void)ws_size;
    const float* x    = (const float*)d_in[0];
    const float* W1   = (const float*)d_in[1];
    const float* b1   = (const float*)d_in[2];
    const float* Wr   = (const float*)d_in[3];
    const float* br   = (const float*)d_in[4];
    const float* Wexp = (const float*)d_in[5];
    const float* bexp = (const float*)d_in[6];
    const float* W2   = (const float*)d_in[7];
    const float* b2   = (const float*)d_in[8];
    float* out = (float*)d_out;

    char* ws = (char*)d_ws;
    __hip_bfloat16* catT = (__hip_bfloat16*)ws;                    // 78,643,200
    __hip_bfloat16* Wts  = (__hip_bfloat16*)(ws + 78643200);       //  1,179,648
    __hip_bfloat16* Wt1s = (__hip_bfloat16*)(ws + 79822848);       //    131,072
    __hip_bfloat16* Wt2s = (__hip_bfloat16*)(ws + 79953920);       //    196,608
    float* pooled        = (float*)(ws + 80150528);                //      8,192
    int*   sel_idx       = (int*)(ws + 80158720);                  //        128
    float* sel_w         = (float*)(ws + 80158848);                //        128

    hipMemsetAsync(pooled, 0, 16 * 128 * 4, stream);
    prep_swz1    <<<dim3(32),         256, 0, stream>>>(W1, Wt1s);
    prep_swz2    <<<dim3(48),         256, 0, stream>>>(W2, Wt2s);
    prep_swzE    <<<dim3(288),        256, 0, stream>>>(Wexp, Wts);
    cv1_fused    <<<dim3(50, 16),     256, 0, stream>>>(x, Wt1s, b1, catT, pooled);
    router_kernel<<<1,                 64, 0, stream>>>(pooled, Wr, br, sel_idx, sel_w);
    expert_cv2   <<<dim3(800),        256, 0, stream>>>(catT, Wts, bexp, sel_idx, sel_w,
                                                        Wt2s, b2, out);
}